// Round 2
// baseline (102.620 us; speedup 1.0000x reference)
//
#include <hip/hip_runtime.h>

#define NB 2
#define SQL 256
#define NH 16
#define HD 64
#define EMB 1024

// log2(e) / sqrt(EMBED): folded into Wq so softmax = 2^(q*k)
__device__ __constant__ float kQSCALE = 1.4426950408889634f / 32.0f;

__device__ __forceinline__ float fexp2(float x) { return __builtin_amdgcn_exp2f(x); }
__device__ __forceinline__ float frcp(float x)  { return __builtin_amdgcn_rcpf(x); }

// ---------------------------------------------------------------------------
// Kernel 1: q/k/v projections. TWO blocks per (n,s): each computes 32 of the
// 64 e-outputs. Output layout [ns][e][h] (h contiguous, 16 per e) so the
// attention lane e reads 16 contiguous floats. Wq pre-scaled by kQSCALE.
// Grid 1024, LDS ~30 KB -> ~5 blocks/CU.
// ---------------------------------------------------------------------------
__global__ __launch_bounds__(256) void qkv_kernel(
    const float* __restrict__ x,
    const float* __restrict__ Wq,
    const float* __restrict__ Wk,
    const float* __restrict__ Wv,
    float* __restrict__ Q,
    float* __restrict__ K,
    float* __restrict__ V)
{
    __shared__ float wq[32 * 68];
    __shared__ float wk[32 * 68];
    __shared__ float wv[32 * 68];
    __shared__ float xs[16 * 68];

    const int tid  = threadIdx.x;
    const int ns   = blockIdx.x >> 1;
    const int half = blockIdx.x & 1;

    // stage x row: [h=16][d=64] -> xs[h*68 + d]
    {
        const int h  = tid >> 4;
        const int d0 = (tid & 15) * 4;
        const float4 a = ((const float4*)(x + (size_t)ns * EMB))[tid];
        *(float4*)&xs[h * 68 + d0] = a;
    }
    // stage weight rows e0..e0+31 (512 float4s per matrix, 2 per thread)
#pragma unroll
    for (int j = 0; j < 2; ++j) {
        const int f4 = j * 256 + tid;
        const int e  = f4 >> 4;          // 0..31 local
        const int d4 = f4 & 15;
        const int g  = half * 512 + f4;  // global float4 index
        float4 a = ((const float4*)Wq)[g];
        a.x *= kQSCALE; a.y *= kQSCALE; a.z *= kQSCALE; a.w *= kQSCALE;
        *(float4*)&wq[e * 68 + d4 * 4] = a;
        *(float4*)&wk[e * 68 + d4 * 4] = ((const float4*)Wk)[g];
        *(float4*)&wv[e * 68 + d4 * 4] = ((const float4*)Wv)[g];
    }
    __syncthreads();

    const int el = tid >> 3;        // local e, 0..31
    const int h0 = (tid & 7) * 2;   // h pair

    float aq[2] = {0.f, 0.f}, ak[2] = {0.f, 0.f}, av[2] = {0.f, 0.f};

#pragma unroll
    for (int d4 = 0; d4 < 16; ++d4) {
        const float4 wqv = *(const float4*)&wq[el * 68 + d4 * 4];
        const float4 wkv = *(const float4*)&wk[el * 68 + d4 * 4];
        const float4 wvv = *(const float4*)&wv[el * 68 + d4 * 4];
#pragma unroll
        for (int hh = 0; hh < 2; ++hh) {
            const float4 xv = *(const float4*)&xs[(h0 + hh) * 68 + d4 * 4];
            aq[hh] = fmaf(xv.x, wqv.x, fmaf(xv.y, wqv.y, fmaf(xv.z, wqv.z, fmaf(xv.w, wqv.w, aq[hh]))));
            ak[hh] = fmaf(xv.x, wkv.x, fmaf(xv.y, wkv.y, fmaf(xv.z, wkv.z, fmaf(xv.w, wkv.w, ak[hh]))));
            av[hh] = fmaf(xv.x, wvv.x, fmaf(xv.y, wvv.y, fmaf(xv.z, wvv.z, fmaf(xv.w, wvv.w, av[hh]))));
        }
    }
    // output float2 at offset (e0+el)*16 + h0 == half*512 + 2*tid
    const size_t off = (size_t)ns * EMB + half * 512 + 2 * tid;
    *(float2*)&Q[off] = make_float2(aq[0], aq[1]);
    *(float2*)&K[off] = make_float2(ak[0], ak[1]);
    *(float2*)&V[off] = make_float2(av[0], av[1]);
}

// ---------------------------------------------------------------------------
// Kernel 2: fused elementwise-energy -> softmax over h (16) -> sum over t.
// Lane = e. Each wave owns 2 s-values; block = 8 s-values x 16-wide t-chunk.
// Grid = 2n * 32st * 16tc = 1024 blocks (16 waves/CU). atomicAdd partials.
// ---------------------------------------------------------------------------
__global__ __launch_bounds__(256, 4) void attn_kernel(
    const float* __restrict__ Q,
    const float* __restrict__ K,
    const float* __restrict__ V,
    float* __restrict__ AO)
{
    const int b    = blockIdx.x;
    const int tc   = b & 15;
    const int st   = (b >> 4) & 31;
    const int n    = b >> 9;
    const int wave = threadIdx.x >> 6;
    const int d    = threadIdx.x & 63;  // = e
    const int s0   = st * 8 + wave * 2;

    float q0[16], q1[16], acc0[16], acc1[16];
    {
        const float4* qp0 = (const float4*)(Q + ((size_t)(n * SQL + s0) * 64 + d) * 16);
        const float4* qp1 = (const float4*)(Q + ((size_t)(n * SQL + s0 + 1) * 64 + d) * 16);
#pragma unroll
        for (int j = 0; j < 4; ++j) {
            const float4 a = qp0[j];
            q0[4 * j + 0] = a.x; q0[4 * j + 1] = a.y; q0[4 * j + 2] = a.z; q0[4 * j + 3] = a.w;
            const float4 c = qp1[j];
            q1[4 * j + 0] = c.x; q1[4 * j + 1] = c.y; q1[4 * j + 2] = c.z; q1[4 * j + 3] = c.w;
        }
    }
#pragma unroll
    for (int h = 0; h < 16; ++h) { acc0[h] = 0.f; acc1[h] = 0.f; }

    const int t0 = tc * 16;
    for (int tt = 0; tt < 16; ++tt) {
        const int t = t0 + tt;
        const float4* kp = (const float4*)(K + ((size_t)(n * SQL + t) * 64 + d) * 16);
        const float4* vp = (const float4*)(V + ((size_t)(n * SQL + t) * 64 + d) * 16);
        float kv[16], vv[16];
#pragma unroll
        for (int j = 0; j < 4; ++j) {
            const float4 a = kp[j];
            kv[4 * j + 0] = a.x; kv[4 * j + 1] = a.y; kv[4 * j + 2] = a.z; kv[4 * j + 3] = a.w;
            const float4 c = vp[j];
            vv[4 * j + 0] = c.x; vv[4 * j + 1] = c.y; vv[4 * j + 2] = c.z; vv[4 * j + 3] = c.w;
        }
        float p0[16], p1[16];
#pragma unroll
        for (int h = 0; h < 16; ++h) {
            p0[h] = fexp2(q0[h] * kv[h]);
            p1[h] = fexp2(q1[h] * kv[h]);
        }
        float a0 = (p0[0] + p0[8])  + (p0[4] + p0[12]);
        float a1 = (p0[1] + p0[9])  + (p0[5] + p0[13]);
        float a2 = (p0[2] + p0[10]) + (p0[6] + p0[14]);
        float a3 = (p0[3] + p0[11]) + (p0[7] + p0[15]);
        float b0 = (p1[0] + p1[8])  + (p1[4] + p1[12]);
        float b1 = (p1[1] + p1[9])  + (p1[5] + p1[13]);
        float b2 = (p1[2] + p1[10]) + (p1[6] + p1[14]);
        float b3 = (p1[3] + p1[11]) + (p1[7] + p1[15]);
        const float rs0 = frcp((a0 + a1) + (a2 + a3));
        const float rs1 = frcp((b0 + b1) + (b2 + b3));
#pragma unroll
        for (int h = 0; h < 16; ++h) {
            acc0[h] = fmaf(p0[h] * rs0, vv[h], acc0[h]);
            acc1[h] = fmaf(p1[h] * rs1, vv[h], acc1[h]);
        }
    }

    float* ao0 = AO + (size_t)(n * SQL + s0) * EMB + d;
    float* ao1 = AO + (size_t)(n * SQL + s0 + 1) * EMB + d;
#pragma unroll
    for (int h = 0; h < 16; ++h) {
        atomicAdd(ao0 + h * 64, acc0[h]);
        atomicAdd(ao1 + h * 64, acc1[h]);
    }
}

// ---------------------------------------------------------------------------
// Kernel 3: out = AO @ Wo^T (f32 vector GEMM). 64r x 32j tile, k-split 4.
// Grid = 8rt * 32jt * 4kc = 1024 blocks. Deterministic partials P[kc].
// ---------------------------------------------------------------------------
__global__ __launch_bounds__(256) void proj_kernel(
    const float* __restrict__ A,
    const float* __restrict__ Wo,
    float* __restrict__ P)
{
    __shared__ float As[32][68];
    __shared__ float Ws[32][36];

    const int b  = blockIdx.x;
    const int kc = b & 3;
    const int jt = (b >> 2) & 31;
    const int rt = b >> 7;
    const int tid = threadIdx.x;
    const int tx = tid & 15;
    const int ty = tid >> 4;
    const int r0 = rt * 64, j0 = jt * 32, k0 = kc * 256;

    float2 c2[4];
#pragma unroll
    for (int i = 0; i < 4; ++i) c2[i] = make_float2(0.f, 0.f);

    for (int kt = 0; kt < 8; ++kt) {
        const int kb = k0 + kt * 32;
        __syncthreads();
        // A tile: 64 rows x 32 k (512 float4s, 2/thread), stored transposed
#pragma unroll
        for (int it = 0; it < 2; ++it) {
            const int f   = it * 256 + tid;
            const int row = f >> 3;
            const int kq  = f & 7;
            const float4 a = *(const float4*)&A[(size_t)(r0 + row) * EMB + kb + kq * 4];
            As[kq * 4 + 0][row] = a.x;
            As[kq * 4 + 1][row] = a.y;
            As[kq * 4 + 2][row] = a.z;
            As[kq * 4 + 3][row] = a.w;
        }
        // W tile: 32 rows x 32 k (256 float4s, 1/thread), stored transposed
        {
            const int row = tid >> 3;
            const int kq  = tid & 7;
            const float4 w = *(const float4*)&Wo[(size_t)(j0 + row) * EMB + kb + kq * 4];
            Ws[kq * 4 + 0][row] = w.x;
            Ws[kq * 4 + 1][row] = w.y;
            Ws[kq * 4 + 2][row] = w.z;
            Ws[kq * 4 + 3][row] = w.w;
        }
        __syncthreads();
#pragma unroll
        for (int kk = 0; kk < 32; ++kk) {
            const float4 a4 = *(const float4*)&As[kk][ty * 4];
            const float2 w2 = *(const float2*)&Ws[kk][tx * 2];
            c2[0].x = fmaf(a4.x, w2.x, c2[0].x); c2[0].y = fmaf(a4.x, w2.y, c2[0].y);
            c2[1].x = fmaf(a4.y, w2.x, c2[1].x); c2[1].y = fmaf(a4.y, w2.y, c2[1].y);
            c2[2].x = fmaf(a4.z, w2.x, c2[2].x); c2[2].y = fmaf(a4.z, w2.y, c2[2].y);
            c2[3].x = fmaf(a4.w, w2.x, c2[3].x); c2[3].y = fmaf(a4.w, w2.y, c2[3].y);
        }
    }

    float* p = P + (size_t)kc * 524288;
#pragma unroll
    for (int rr = 0; rr < 4; ++rr) {
        *(float2*)&p[(size_t)(r0 + ty * 4 + rr) * EMB + j0 + tx * 2] = c2[rr];
    }
}

__global__ __launch_bounds__(256) void reduce_kernel(
    const float* __restrict__ P,
    const float* __restrict__ bo,
    float* __restrict__ out)
{
    const int f4 = blockIdx.x * 256 + threadIdx.x;   // 131072 float4s
    const float4* P4 = (const float4*)P;
    const float4 a = P4[f4];
    const float4 b = P4[131072 + f4];
    const float4 c = P4[262144 + f4];
    const float4 d = P4[393216 + f4];
    const float4 bb = ((const float4*)bo)[f4 & 255];
    float4 o;
    o.x = ((a.x + b.x) + (c.x + d.x)) + bb.x;
    o.y = ((a.y + b.y) + (c.y + d.y)) + bb.y;
    o.z = ((a.z + b.z) + (c.z + d.z)) + bb.z;
    o.w = ((a.w + b.w) + (c.w + d.w)) + bb.w;
    ((float4*)out)[f4] = o;
}

extern "C" void kernel_launch(void* const* d_in, const int* in_sizes, int n_in,
                              void* d_out, int out_size, void* d_ws, size_t ws_size,
                              hipStream_t stream)
{
    const float* x  = (const float*)d_in[0];
    const float* Wq = (const float*)d_in[1];
    const float* Wk = (const float*)d_in[2];
    const float* Wv = (const float*)d_in[3];
    const float* Wo = (const float*)d_in[4];
    const float* bo = (const float*)d_in[5];

    float* ws = (float*)d_ws;
    float* Q  = ws;                 // 524288 floats
    float* K  = ws + 524288;        // 524288
    float* V  = ws + 1048576;       // 524288
    float* AO = ws + 1572864;       // 524288
    float* P  = ws + 2097152;       // 4 * 524288

    hipMemsetAsync(AO, 0, 524288 * sizeof(float), stream);
    qkv_kernel<<<1024, 256, 0, stream>>>(x, Wq, Wk, Wv, Q, K, V);
    attn_kernel<<<1024, 256, 0, stream>>>(Q, K, V, AO);
    proj_kernel<<<1024, 256, 0, stream>>>(AO, Wo, P);
    reduce_kernel<<<512, 256, 0, stream>>>(P, bo, (float*)d_out);
}

// Round 3
// 101.576 us; speedup vs baseline: 1.0103x; 1.0103x over previous
//
#include <hip/hip_runtime.h>

#define NB 2
#define SQL 256
#define NH 16
#define HD 64
#define EMB 1024

// log2(e) / sqrt(EMBED): folded into Wq so softmax = 2^(q*k)
__device__ __constant__ float kQSCALE = 1.4426950408889634f / 32.0f;

__device__ __forceinline__ float fexp2(float x) { return __builtin_amdgcn_exp2f(x); }
__device__ __forceinline__ float frcp(float x)  { return __builtin_amdgcn_rcpf(x); }

__device__ __forceinline__ float4 pexp2(float4 q, float4 k) {
    return make_float4(fexp2(q.x * k.x), fexp2(q.y * k.y),
                       fexp2(q.z * k.z), fexp2(q.w * k.w));
}
__device__ __forceinline__ float hsum4(float4 a, float4 b, float4 c, float4 d) {
    float s0 = (a.x + a.y) + (a.z + a.w);
    float s1 = (b.x + b.y) + (b.z + b.w);
    float s2 = (c.x + c.y) + (c.z + c.w);
    float s3 = (d.x + d.y) + (d.z + d.w);
    return (s0 + s1) + (s2 + s3);
}
__device__ __forceinline__ void paccum(float4& a, float4 p, float rs, float4 v) {
    a.x = fmaf(p.x * rs, v.x, a.x);
    a.y = fmaf(p.y * rs, v.y, a.y);
    a.z = fmaf(p.z * rs, v.z, a.z);
    a.w = fmaf(p.w * rs, v.w, a.w);
}

// ---------------------------------------------------------------------------
// Kernel 1: q/k/v projections. TWO blocks per (n,s): each computes 32 of the
// 64 e-outputs. Output layout [ns][e][h] (h contiguous, 16 per e). Wq is
// pre-scaled by kQSCALE.
// ---------------------------------------------------------------------------
__global__ __launch_bounds__(256) void qkv_kernel(
    const float* __restrict__ x,
    const float* __restrict__ Wq,
    const float* __restrict__ Wk,
    const float* __restrict__ Wv,
    float* __restrict__ Q,
    float* __restrict__ K,
    float* __restrict__ V)
{
    __shared__ float wq[32 * 68];
    __shared__ float wk[32 * 68];
    __shared__ float wv[32 * 68];
    __shared__ float xs[16 * 68];

    const int tid  = threadIdx.x;
    const int ns   = blockIdx.x >> 1;
    const int half = blockIdx.x & 1;

    {
        const int h  = tid >> 4;
        const int d0 = (tid & 15) * 4;
        const float4 a = ((const float4*)(x + (size_t)ns * EMB))[tid];
        *(float4*)&xs[h * 68 + d0] = a;
    }
#pragma unroll
    for (int j = 0; j < 2; ++j) {
        const int f4 = j * 256 + tid;
        const int e  = f4 >> 4;
        const int d4 = f4 & 15;
        const int g  = half * 512 + f4;
        float4 a = ((const float4*)Wq)[g];
        a.x *= kQSCALE; a.y *= kQSCALE; a.z *= kQSCALE; a.w *= kQSCALE;
        *(float4*)&wq[e * 68 + d4 * 4] = a;
        *(float4*)&wk[e * 68 + d4 * 4] = ((const float4*)Wk)[g];
        *(float4*)&wv[e * 68 + d4 * 4] = ((const float4*)Wv)[g];
    }
    __syncthreads();

    const int el = tid >> 3;
    const int h0 = (tid & 7) * 2;

    float aq[2] = {0.f, 0.f}, ak[2] = {0.f, 0.f}, av[2] = {0.f, 0.f};

#pragma unroll
    for (int d4 = 0; d4 < 16; ++d4) {
        const float4 wqv = *(const float4*)&wq[el * 68 + d4 * 4];
        const float4 wkv = *(const float4*)&wk[el * 68 + d4 * 4];
        const float4 wvv = *(const float4*)&wv[el * 68 + d4 * 4];
#pragma unroll
        for (int hh = 0; hh < 2; ++hh) {
            const float4 xv = *(const float4*)&xs[(h0 + hh) * 68 + d4 * 4];
            aq[hh] = fmaf(xv.x, wqv.x, fmaf(xv.y, wqv.y, fmaf(xv.z, wqv.z, fmaf(xv.w, wqv.w, aq[hh]))));
            ak[hh] = fmaf(xv.x, wkv.x, fmaf(xv.y, wkv.y, fmaf(xv.z, wkv.z, fmaf(xv.w, wkv.w, ak[hh]))));
            av[hh] = fmaf(xv.x, wvv.x, fmaf(xv.y, wvv.y, fmaf(xv.z, wvv.z, fmaf(xv.w, wvv.w, av[hh]))));
        }
    }
    const size_t off = (size_t)ns * EMB + half * 512 + 2 * tid;
    *(float2*)&Q[off] = make_float2(aq[0], aq[1]);
    *(float2*)&K[off] = make_float2(ak[0], ak[1]);
    *(float2*)&V[off] = make_float2(av[0], av[1]);
}

// ---------------------------------------------------------------------------
// Kernel 2: fused elementwise-energy -> softmax over h (16) -> sum over t.
// Lane = e. Wave = 2 s-values (serialized streams to bound register
// pressure); block = 8 s x 16-wide t-chunk. Grid 1024. Occupancy pinned at
// 4 waves/EU so the allocator has a firm 128-VGPR budget (round-2 failure:
// allocator chose 60 VGPR + spilled the whole loop state).
// ---------------------------------------------------------------------------
__global__ __attribute__((amdgpu_waves_per_eu(4, 4))) __launch_bounds__(256)
void attn_kernel(
    const float* __restrict__ Q,
    const float* __restrict__ K,
    const float* __restrict__ V,
    float* __restrict__ AO)
{
    const int b    = blockIdx.x;
    const int tc   = b & 15;
    const int st   = (b >> 4) & 31;
    const int n    = b >> 9;
    const int wave = threadIdx.x >> 6;
    const int d    = threadIdx.x & 63;  // = e
    const int s0   = st * 8 + wave * 2;

    float4 q0[4], q1[4], a0[4], a1[4];
    {
        const float4* qp0 = (const float4*)(Q + ((size_t)(n * SQL + s0) * 64 + d) * 16);
        const float4* qp1 = (const float4*)(Q + ((size_t)(n * SQL + s0 + 1) * 64 + d) * 16);
#pragma unroll
        for (int j = 0; j < 4; ++j) { q0[j] = qp0[j]; q1[j] = qp1[j]; }
    }
#pragma unroll
    for (int j = 0; j < 4; ++j) {
        a0[j] = make_float4(0.f, 0.f, 0.f, 0.f);
        a1[j] = make_float4(0.f, 0.f, 0.f, 0.f);
    }

    const int t0 = tc * 16;
    const float4* kp = (const float4*)(K + ((size_t)(n * SQL + t0) * 64 + d) * 16);
    const float4* vp = (const float4*)(V + ((size_t)(n * SQL + t0) * 64 + d) * 16);

    for (int tt = 0; tt < 16; ++tt) {
        const float4 k0 = kp[0], k1 = kp[1], k2 = kp[2], k3 = kp[3];
        const float4 v0 = vp[0], v1 = vp[1], v2 = vp[2], v3 = vp[3];
        kp += 256; vp += 256;
        // ---- s0 stream ----
        {
            float4 p0 = pexp2(q0[0], k0), p1 = pexp2(q0[1], k1);
            float4 p2 = pexp2(q0[2], k2), p3 = pexp2(q0[3], k3);
            const float rs = frcp(hsum4(p0, p1, p2, p3));
            paccum(a0[0], p0, rs, v0);
            paccum(a0[1], p1, rs, v1);
            paccum(a0[2], p2, rs, v2);
            paccum(a0[3], p3, rs, v3);
        }
        __builtin_amdgcn_sched_barrier(0);  // keep s1's 16 exps from co-scheduling with s0's
        // ---- s1 stream ----
        {
            float4 p0 = pexp2(q1[0], k0), p1 = pexp2(q1[1], k1);
            float4 p2 = pexp2(q1[2], k2), p3 = pexp2(q1[3], k3);
            const float rs = frcp(hsum4(p0, p1, p2, p3));
            paccum(a1[0], p0, rs, v0);
            paccum(a1[1], p1, rs, v1);
            paccum(a1[2], p2, rs, v2);
            paccum(a1[3], p3, rs, v3);
        }
    }

    float* ao0 = AO + (size_t)(n * SQL + s0) * EMB + d;
    float* ao1 = AO + (size_t)(n * SQL + s0 + 1) * EMB + d;
#pragma unroll
    for (int j = 0; j < 4; ++j) {
        atomicAdd(ao0 + (4 * j + 0) * 64, a0[j].x);
        atomicAdd(ao0 + (4 * j + 1) * 64, a0[j].y);
        atomicAdd(ao0 + (4 * j + 2) * 64, a0[j].z);
        atomicAdd(ao0 + (4 * j + 3) * 64, a0[j].w);
        atomicAdd(ao1 + (4 * j + 0) * 64, a1[j].x);
        atomicAdd(ao1 + (4 * j + 1) * 64, a1[j].y);
        atomicAdd(ao1 + (4 * j + 2) * 64, a1[j].z);
        atomicAdd(ao1 + (4 * j + 3) * 64, a1[j].w);
    }
}

// ---------------------------------------------------------------------------
// Kernel 3: out = AO @ Wo^T (f32 vector GEMM). 64r x 32j tile, k-split 4.
// Grid = 8rt * 32jt * 4kc = 1024 blocks. Deterministic partials P[kc].
// ---------------------------------------------------------------------------
__global__ __launch_bounds__(256) void proj_kernel(
    const float* __restrict__ A,
    const float* __restrict__ Wo,
    float* __restrict__ P)
{
    __shared__ float As[32][68];
    __shared__ float Ws[32][36];

    const int b  = blockIdx.x;
    const int kc = b & 3;
    const int jt = (b >> 2) & 31;
    const int rt = b >> 7;
    const int tid = threadIdx.x;
    const int tx = tid & 15;
    const int ty = tid >> 4;
    const int r0 = rt * 64, j0 = jt * 32, k0 = kc * 256;

    float2 c2[4];
#pragma unroll
    for (int i = 0; i < 4; ++i) c2[i] = make_float2(0.f, 0.f);

    for (int kt = 0; kt < 8; ++kt) {
        const int kb = k0 + kt * 32;
        __syncthreads();
#pragma unroll
        for (int it = 0; it < 2; ++it) {
            const int f   = it * 256 + tid;
            const int row = f >> 3;
            const int kq  = f & 7;
            const float4 a = *(const float4*)&A[(size_t)(r0 + row) * EMB + kb + kq * 4];
            As[kq * 4 + 0][row] = a.x;
            As[kq * 4 + 1][row] = a.y;
            As[kq * 4 + 2][row] = a.z;
            As[kq * 4 + 3][row] = a.w;
        }
        {
            const int row = tid >> 3;
            const int kq  = tid & 7;
            const float4 w = *(const float4*)&Wo[(size_t)(j0 + row) * EMB + kb + kq * 4];
            Ws[kq * 4 + 0][row] = w.x;
            Ws[kq * 4 + 1][row] = w.y;
            Ws[kq * 4 + 2][row] = w.z;
            Ws[kq * 4 + 3][row] = w.w;
        }
        __syncthreads();
#pragma unroll
        for (int kk = 0; kk < 32; ++kk) {
            const float4 a4 = *(const float4*)&As[kk][ty * 4];
            const float2 w2 = *(const float2*)&Ws[kk][tx * 2];
            c2[0].x = fmaf(a4.x, w2.x, c2[0].x); c2[0].y = fmaf(a4.x, w2.y, c2[0].y);
            c2[1].x = fmaf(a4.y, w2.x, c2[1].x); c2[1].y = fmaf(a4.y, w2.y, c2[1].y);
            c2[2].x = fmaf(a4.z, w2.x, c2[2].x); c2[2].y = fmaf(a4.z, w2.y, c2[2].y);
            c2[3].x = fmaf(a4.w, w2.x, c2[3].x); c2[3].y = fmaf(a4.w, w2.y, c2[3].y);
        }
    }

    float* p = P + (size_t)kc * 524288;
#pragma unroll
    for (int rr = 0; rr < 4; ++rr) {
        *(float2*)&p[(size_t)(r0 + ty * 4 + rr) * EMB + j0 + tx * 2] = c2[rr];
    }
}

__global__ __launch_bounds__(256) void reduce_kernel(
    const float* __restrict__ P,
    const float* __restrict__ bo,
    float* __restrict__ out)
{
    const int f4 = blockIdx.x * 256 + threadIdx.x;   // 131072 float4s
    const float4* P4 = (const float4*)P;
    const float4 a = P4[f4];
    const float4 b = P4[131072 + f4];
    const float4 c = P4[262144 + f4];
    const float4 d = P4[393216 + f4];
    const float4 bb = ((const float4*)bo)[f4 & 255];
    float4 o;
    o.x = ((a.x + b.x) + (c.x + d.x)) + bb.x;
    o.y = ((a.y + b.y) + (c.y + d.y)) + bb.y;
    o.z = ((a.z + b.z) + (c.z + d.z)) + bb.z;
    o.w = ((a.w + b.w) + (c.w + d.w)) + bb.w;
    ((float4*)out)[f4] = o;
}

extern "C" void kernel_launch(void* const* d_in, const int* in_sizes, int n_in,
                              void* d_out, int out_size, void* d_ws, size_t ws_size,
                              hipStream_t stream)
{
    const float* x  = (const float*)d_in[0];
    const float* Wq = (const float*)d_in[1];
    const float* Wk = (const float*)d_in[2];
    const float* Wv = (const float*)d_in[3];
    const float* Wo = (const float*)d_in[4];
    const float* bo = (const float*)d_in[5];

    float* ws = (float*)d_ws;
    float* Q  = ws;                 // 524288 floats
    float* K  = ws + 524288;        // 524288
    float* V  = ws + 1048576;       // 524288
    float* AO = ws + 1572864;       // 524288
    float* P  = ws + 2097152;       // 4 * 524288

    hipMemsetAsync(AO, 0, 524288 * sizeof(float), stream);
    qkv_kernel<<<1024, 256, 0, stream>>>(x, Wq, Wk, Wv, Q, K, V);
    attn_kernel<<<1024, 256, 0, stream>>>(Q, K, V, AO);
    proj_kernel<<<1024, 256, 0, stream>>>(AO, Wo, P);
    reduce_kernel<<<512, 256, 0, stream>>>(P, bo, (float*)d_out);
}